// Round 19
// baseline (199.418 us; speedup 1.0000x reference)
//
#include <hip/hip_runtime.h>
#include <math.h>

// Problem constants
#define BATCH 64
#define N_ATOMS 512
#define NE 500
#define FIELD_DIM 256
#define E_DIM 64
#define HIDDEN 512
#define LATENT 256

typedef short bf16x8 __attribute__((ext_vector_type(8)));
typedef unsigned short u16x8 __attribute__((ext_vector_type(8)));
typedef unsigned short u16x4 __attribute__((ext_vector_type(4)));
typedef float f32x4 __attribute__((ext_vector_type(4)));

__device__ __forceinline__ unsigned short f2bf(float x) {
    unsigned u = __float_as_uint(x);
    unsigned r = (u + 0x7FFFu + ((u >> 16) & 1u)) >> 16;
    return (unsigned short)r;
}
__device__ __forceinline__ float bf2f(unsigned short b) {
    return __uint_as_float(((unsigned)b) << 16);
}
__device__ __forceinline__ float silu_f(float x) { return x / (1.f + __expf(-x)); }

#define GLOAD_LDS16(gptr, lptr)                                                   \
    __builtin_amdgcn_global_load_lds(                                             \
        (const __attribute__((address_space(1))) void*)(gptr),                    \
        (__attribute__((address_space(3))) void*)(lptr), 16, 0, 0)

// weight offsets inside wt (ushort units), order q1,q2,q3,k1,k2,k3,v1,v2,v3,o1,o2
#define QW1 0
#define QW2 32768
#define QW3 294912
#define KW1 425984
#define KW2 557056
#define KW3 819200
#define VW1 950272
#define VW2 1081344
#define VW3 1343488
#define OW1 1474560
#define OW2 1605632

// ===========================================================================
// 32-ROW in-place MLP layer for fused_qkv (32KB LDS, 4 blocks/CU).
// 8 waves; wave computes 64 features over 32 rows (nf<2).
// Packed weights: (( (wave*4+mf)*NS + ks)*64 + lane)*8. Depth-1 prefetch.
// D mapping (validated r4-r18): feature = fq*4+r, act-row = fr.
// ===========================================================================
template <int K, bool SILU>
__device__ __forceinline__ void mlp_layer_ip32(
    const unsigned short* __restrict__ Wg, const float* __restrict__ Bg,
    unsigned short* buf, int wave, int lane, int fr, int fq)
{
    constexpr int NS = K / 32;
    const int fb = wave * 64;
    const unsigned short* wp = Wg + (long long)(wave * 4) * NS * 512 + lane * 8;

    f32x4 acc[4][2];
#pragma unroll
    for (int mf = 0; mf < 4; mf++)
#pragma unroll
        for (int nf = 0; nf < 2; nf++) acc[mf][nf] = (f32x4)0.f;

    bf16x8 wfA[4];
#pragma unroll
    for (int mf = 0; mf < 4; mf++)
        wfA[mf] = *reinterpret_cast<const bf16x8*>(wp + (long long)mf * NS * 512);

#pragma unroll
    for (int ks = 0; ks < NS; ks++) {
        bf16x8 wfB[4];
        if (ks + 1 < NS) {
#pragma unroll
            for (int mf = 0; mf < 4; mf++)
                wfB[mf] = *reinterpret_cast<const bf16x8*>(
                    wp + ((long long)mf * NS + (ks + 1)) * 512);
        }
        bf16x8 bfr[2];
#pragma unroll
        for (int nf = 0; nf < 2; nf++) {
            int row = nf * 16 + fr;
            bfr[nf] = *reinterpret_cast<const bf16x8*>(
                (const char*)buf + row * (K * 2) +
                ((ks * 64 + fq * 16) ^ ((row & 7) << 4)));
        }
        __builtin_amdgcn_s_setprio(1);
#pragma unroll
        for (int mf = 0; mf < 4; mf++)
#pragma unroll
            for (int nf = 0; nf < 2; nf++)
                acc[mf][nf] = __builtin_amdgcn_mfma_f32_16x16x32_bf16(
                    wfA[mf], bfr[nf], acc[mf][nf], 0, 0, 0);
        __builtin_amdgcn_s_setprio(0);
        if (ks + 1 < NS) {
#pragma unroll
            for (int mf = 0; mf < 4; mf++) wfA[mf] = wfB[mf];
        }
    }
    __syncthreads();   // all reads complete before in-place overwrite

#pragma unroll
    for (int mf = 0; mf < 4; mf++) {
        f32x4 bv = *reinterpret_cast<const f32x4*>(Bg + fb + mf * 16 + fq * 4);
#pragma unroll
        for (int nf = 0; nf < 2; nf++) {
            int row = nf * 16 + fr;
            u16x4 ov;
#pragma unroll
            for (int r = 0; r < 4; r++) {
                float x = acc[mf][nf][r] + bv[r];
                if (SILU) x = silu_f(x);
                ov[r] = f2bf(x);
            }
            *reinterpret_cast<u16x4*>(
                (char*)buf + row * 1024 +
                ((fb * 2 + mf * 32 + fq * 8) ^ ((row & 7) << 4))) = ov;
        }
    }
    __syncthreads();
}

// 32-row final layer: [32][512] -> 256 features (wave does 32), acc[2][2]
__device__ __forceinline__ void mlp_final32(
    const unsigned short* __restrict__ Wg, const float* __restrict__ Bg,
    const unsigned short* buf, int wave, int lane, int fr, int fq,
    f32x4 (&acc)[2][2])
{
    const int fb = wave * 32;
    const unsigned short* wp = Wg + (long long)(wave * 2) * 16 * 512 + lane * 8;
#pragma unroll
    for (int mf = 0; mf < 2; mf++)
#pragma unroll
        for (int nf = 0; nf < 2; nf++) acc[mf][nf] = (f32x4)0.f;

    bf16x8 wfA[2];
#pragma unroll
    for (int mf = 0; mf < 2; mf++)
        wfA[mf] = *reinterpret_cast<const bf16x8*>(wp + (long long)mf * 16 * 512);

#pragma unroll
    for (int ks = 0; ks < 16; ks++) {
        bf16x8 wfB[2];
        if (ks + 1 < 16) {
#pragma unroll
            for (int mf = 0; mf < 2; mf++)
                wfB[mf] = *reinterpret_cast<const bf16x8*>(
                    wp + ((long long)mf * 16 + (ks + 1)) * 512);
        }
        bf16x8 bfr[2];
#pragma unroll
        for (int nf = 0; nf < 2; nf++) {
            int row = nf * 16 + fr;
            bfr[nf] = *reinterpret_cast<const bf16x8*>(
                (const char*)buf + row * 1024 +
                ((ks * 64 + fq * 16) ^ ((row & 7) << 4)));
        }
        __builtin_amdgcn_s_setprio(1);
#pragma unroll
        for (int mf = 0; mf < 2; mf++)
#pragma unroll
            for (int nf = 0; nf < 2; nf++)
                acc[mf][nf] = __builtin_amdgcn_mfma_f32_16x16x32_bf16(
                    wfA[mf], bfr[nf], acc[mf][nf], 0, 0, 0);
        __builtin_amdgcn_s_setprio(0);
        if (ks + 1 < 16) {
#pragma unroll
            for (int mf = 0; mf < 2; mf++) wfA[mf] = wfB[mf];
        }
    }
#pragma unroll
    for (int mf = 0; mf < 2; mf++) {
        f32x4 bv = *reinterpret_cast<const f32x4*>(Bg + fb + mf * 16 + fq * 4);
#pragma unroll
        for (int nf = 0; nf < 2; nf++)
#pragma unroll
            for (int r = 0; r < 4; r++) acc[mf][nf][r] += bv[r];
    }
}

// ===========================================================================
// 64-row helpers (r13, unchanged) for the attn o-phase.
// ===========================================================================
template <int K, bool SILU>
__device__ __forceinline__ void mlp_layer_io(
    const unsigned short* __restrict__ Wg, const float* __restrict__ Bg,
    const unsigned short* inb, unsigned short* outb, int wave, int lane,
    int fr, int fq)
{
    constexpr int NS = K / 32;
    const int fb = wave * 64;
    const unsigned short* wp = Wg + (long long)(wave * 4) * NS * 512 + lane * 8;

    f32x4 acc[4][4];
#pragma unroll
    for (int mf = 0; mf < 4; mf++)
#pragma unroll
        for (int nf = 0; nf < 4; nf++) acc[mf][nf] = (f32x4)0.f;

    bf16x8 wfA[4];
#pragma unroll
    for (int mf = 0; mf < 4; mf++)
        wfA[mf] = *reinterpret_cast<const bf16x8*>(wp + (long long)mf * NS * 512);

#pragma unroll
    for (int ks = 0; ks < NS; ks++) {
        bf16x8 wfB[4];
        if (ks + 1 < NS) {
#pragma unroll
            for (int mf = 0; mf < 4; mf++)
                wfB[mf] = *reinterpret_cast<const bf16x8*>(
                    wp + ((long long)mf * NS + (ks + 1)) * 512);
        }
        bf16x8 bfr[4];
#pragma unroll
        for (int nf = 0; nf < 4; nf++) {
            int row = nf * 16 + fr;
            bfr[nf] = *reinterpret_cast<const bf16x8*>(
                (const char*)inb + row * (K * 2) +
                ((ks * 64 + fq * 16) ^ ((row & 7) << 4)));
        }
        __builtin_amdgcn_s_setprio(1);
#pragma unroll
        for (int mf = 0; mf < 4; mf++)
#pragma unroll
            for (int nf = 0; nf < 4; nf++)
                acc[mf][nf] = __builtin_amdgcn_mfma_f32_16x16x32_bf16(
                    wfA[mf], bfr[nf], acc[mf][nf], 0, 0, 0);
        __builtin_amdgcn_s_setprio(0);
        if (ks + 1 < NS) {
#pragma unroll
            for (int mf = 0; mf < 4; mf++) wfA[mf] = wfB[mf];
        }
    }

#pragma unroll
    for (int mf = 0; mf < 4; mf++) {
        f32x4 bv = *reinterpret_cast<const f32x4*>(Bg + fb + mf * 16 + fq * 4);
#pragma unroll
        for (int nf = 0; nf < 4; nf++) {
            int row = nf * 16 + fr;
            u16x4 ov;
#pragma unroll
            for (int r = 0; r < 4; r++) {
                float x = acc[mf][nf][r] + bv[r];
                if (SILU) x = silu_f(x);
                ov[r] = f2bf(x);
            }
            *reinterpret_cast<u16x4*>(
                (char*)outb + row * 1024 +
                ((fb * 2 + mf * 32 + fq * 8) ^ ((row & 7) << 4))) = ov;
        }
    }
    __syncthreads();
}

__device__ __forceinline__ void mlp_final512(
    const unsigned short* __restrict__ Wg, const float* __restrict__ Bg,
    const unsigned short* buf, int wave, int lane, int fr, int fq,
    f32x4 (&acc)[2][4])
{
    const int fb = wave * 32;
    const unsigned short* wp = Wg + (long long)(wave * 2) * 16 * 512 + lane * 8;
#pragma unroll
    for (int mf = 0; mf < 2; mf++)
#pragma unroll
        for (int nf = 0; nf < 4; nf++) acc[mf][nf] = (f32x4)0.f;

    bf16x8 wfA[2];
#pragma unroll
    for (int mf = 0; mf < 2; mf++)
        wfA[mf] = *reinterpret_cast<const bf16x8*>(wp + (long long)mf * 16 * 512);

#pragma unroll
    for (int ks = 0; ks < 16; ks++) {
        bf16x8 wfB[2];
        if (ks + 1 < 16) {
#pragma unroll
            for (int mf = 0; mf < 2; mf++)
                wfB[mf] = *reinterpret_cast<const bf16x8*>(
                    wp + ((long long)mf * 16 + (ks + 1)) * 512);
        }
        bf16x8 bfr[4];
#pragma unroll
        for (int nf = 0; nf < 4; nf++) {
            int row = nf * 16 + fr;
            bfr[nf] = *reinterpret_cast<const bf16x8*>(
                (const char*)buf + row * 1024 +
                ((ks * 64 + fq * 16) ^ ((row & 7) << 4)));
        }
        __builtin_amdgcn_s_setprio(1);
#pragma unroll
        for (int mf = 0; mf < 2; mf++)
#pragma unroll
            for (int nf = 0; nf < 4; nf++)
                acc[mf][nf] = __builtin_amdgcn_mfma_f32_16x16x32_bf16(
                    wfA[mf], bfr[nf], acc[mf][nf], 0, 0, 0);
        __builtin_amdgcn_s_setprio(0);
        if (ks + 1 < 16) {
#pragma unroll
            for (int mf = 0; mf < 2; mf++) wfA[mf] = wfB[mf];
        }
    }
#pragma unroll
    for (int mf = 0; mf < 2; mf++) {
        f32x4 bv = *reinterpret_cast<const f32x4*>(Bg + fb + mf * 16 + fq * 4);
#pragma unroll
        for (int nf = 0; nf < 4; nf++)
#pragma unroll
            for (int r = 0; r < 4; r++) acc[mf][nf][r] += bv[r];
    }
}

// ===========================================================================
// q + k + v MLPs, 32 rows/block. blocks 0-1023: k, 1024-2047: v, 2048-2063: q.
// 32KB LDS, __launch_bounds__(512,4) -> 4 blocks/CU (32 waves = HW max).
// ===========================================================================
__global__ __launch_bounds__(512, 4) void fused_qkv(
    const unsigned short* __restrict__ field_bf,  // [32768][256]
    const unsigned short* __restrict__ efeat_bf,  // [500][64]
    const unsigned short* __restrict__ wt,
    const float* __restrict__ qb1, const float* __restrict__ qb2,
    const float* __restrict__ qb3, const float* __restrict__ kb1,
    const float* __restrict__ kb2, const float* __restrict__ kb3,
    const float* __restrict__ vb1, const float* __restrict__ vb2,
    const float* __restrict__ vb3,
    unsigned short* __restrict__ qbuf,   // [500][256]
    unsigned short* __restrict__ kbuf,   // [32768][256]
    unsigned short* __restrict__ vtb)    // [64][256][512]
{
    __shared__ unsigned short buf[32 * 512];   // 32KB
    const int t = threadIdx.x, wave = t >> 6, lane = t & 63;
    const int fr = lane & 15, fq = lane >> 4;
    const int bid = blockIdx.x;

    if (bid < 2048) {
        const int isv = bid >> 10;
        const int m0  = (bid & 1023) * 32;
        const unsigned short* W1 = wt + (isv ? VW1 : KW1);
        const unsigned short* W2 = wt + (isv ? VW2 : KW2);
        const unsigned short* W3 = wt + (isv ? VW3 : KW3);
        const float* B1 = isv ? vb1 : kb1;
        const float* B2 = isv ? vb2 : kb2;
        const float* B3 = isv ? vb3 : kb3;

        // stage [32][256] (16KB), swizzled source
#pragma unroll
        for (int c = wave; c < 16; c += 8) {
            int gi  = c * 64 + lane;
            int row = gi >> 5;
            int g   = gi & 31;
            int gs  = (g & ~7) | ((g & 7) ^ (row & 7));
            GLOAD_LDS16(field_bf + (long long)(m0 + row) * 256 + gs * 8, buf + c * 512);
        }
        __syncthreads();

        mlp_layer_ip32<256, true>(W1, B1, buf, wave, lane, fr, fq);
        mlp_layer_ip32<512, true>(W2, B2, buf, wave, lane, fr, fq);
        f32x4 acc[2][2];
        mlp_final32(W3, B3, buf, wave, lane, fr, fq, acc);

        if (!isv) {  // k: bf16 [32768][256]
#pragma unroll
            for (int mf = 0; mf < 2; mf++)
#pragma unroll
                for (int nf = 0; nf < 2; nf++) {
                    int row = m0 + nf * 16 + fr;
                    u16x4 ov;
#pragma unroll
                    for (int r = 0; r < 4; r++) ov[r] = f2bf(acc[mf][nf][r]);
                    *reinterpret_cast<u16x4*>(
                        kbuf + (long long)row * 256 + wave * 32 + mf * 16 + fq * 4) = ov;
                }
        } else {     // v: transposed -> vtb[b][256][512]
            __syncthreads();  // final reads done before overwrite
#pragma unroll
            for (int mf = 0; mf < 2; mf++)
#pragma unroll
                for (int nf = 0; nf < 2; nf++) {
                    int row = nf * 16 + fr;
                    u16x4 ov;
#pragma unroll
                    for (int r = 0; r < 4; r++) ov[r] = f2bf(acc[mf][nf][r]);
                    *reinterpret_cast<u16x4*>(
                        (char*)buf + row * 512 +
                        ((wave * 64 + mf * 32 + fq * 8) ^ ((row & 7) << 4))) = ov;
                }
            __syncthreads();
            // transposed store: thread -> (l = t>>1, half of 32 atoms)
            int l  = t >> 1;
            int nh = (t & 1) * 16;
            int b  = m0 >> 9, nb = m0 & 511;
            long long base = ((long long)b * 256 + l) * 512 + nb + nh;
#pragma unroll
            for (int q = 0; q < 2; q++) {
                u16x8 ov;
#pragma unroll
                for (int j = 0; j < 8; j++) {
                    int n = nh + q * 8 + j;
                    ov[j] = *reinterpret_cast<const unsigned short*>(
                        (const char*)buf + n * 512 + ((l * 2) ^ ((n & 7) << 4)));
                }
                *reinterpret_cast<u16x8*>(vtb + base + q * 8) = ov;
            }
        }
    } else {  // q MLP: 16 blocks of 32 rows, M=500, K_IN=64
        const int m0 = (bid - 2048) * 32;
        // stage [32][64] (4KB): waves 0-3 only
        for (int c = wave; c < 4; c += 8) {
            int gi  = c * 64 + lane;
            int row = gi >> 3;
            int g   = gi & 7;
            int gr  = m0 + row; if (gr >= NE) gr = NE - 1;
            int gs  = g ^ (row & 7);
            GLOAD_LDS16(efeat_bf + (long long)gr * 64 + gs * 8, buf + c * 512);
        }
        __syncthreads();

        mlp_layer_ip32<64, true>(wt + QW1, qb1, buf, wave, lane, fr, fq);
        mlp_layer_ip32<512, true>(wt + QW2, qb2, buf, wave, lane, fr, fq);
        f32x4 acc[2][2];
        mlp_final32(wt + QW3, qb3, buf, wave, lane, fr, fq, acc);
#pragma unroll
        for (int mf = 0; mf < 2; mf++)
#pragma unroll
            for (int nf = 0; nf < 2; nf++) {
                int row = m0 + nf * 16 + fr;
                if (row < NE) {
                    u16x4 ov;
#pragma unroll
                    for (int r = 0; r < 4; r++) ov[r] = f2bf(acc[mf][nf][r]);
                    *reinterpret_cast<u16x4*>(
                        qbuf + (long long)row * 256 + wave * 32 + mf * 16 + fq * 4) = ov;
                }
            }
    }
}

// ---------------------------------------------------------------------------
// Fused attention + o-MLP (r13/r17 structure, unchanged).
// ---------------------------------------------------------------------------
__global__ __launch_bounds__(512, 1) void attn_fused(
    const unsigned short* __restrict__ qbuf,   // [NE][256]
    const unsigned short* __restrict__ kbuf,   // [B][512][256]
    const unsigned short* __restrict__ vt,     // [B][256][512]
    const int* __restrict__ mask,              // [B][512]
    const unsigned short* __restrict__ wt,
    const float* __restrict__ ob1, const float* __restrict__ ob2,
    float* __restrict__ out)                   // [B*NE][256] f32
{
    __shared__ unsigned char LDS[100352];
    unsigned short* Qs = (unsigned short*)LDS;             // [4][64][64] 32KB
    unsigned short* Ks = (unsigned short*)(LDS + 32768);   // [512][64]   64KB
    unsigned short* Ps = (unsigned short*)LDS;             // [64][512]   overlay
    unsigned short* Vs = (unsigned short*)(LDS + 65536);   // [256][64]   32KB
    float*          red = (float*)(LDS + 98304);           // [64][8]
    unsigned short* oin  = (unsigned short*)(LDS + 65536); // [64][256] 32KB (o-phase)
    unsigned short* obuf = (unsigned short*)LDS;           // [64][512] 64KB (o-phase)

    const int id = blockIdx.x;
    const int b  = id & 63;
    const int e0 = (id >> 6) * 64;
    const int t = threadIdx.x, wave = t >> 6;
    const int lane = t & 63, fr = lane & 15, fq = lane >> 4;
    const int tr = t >> 3, tg = t & 7;

#pragma unroll
    for (int i = 0; i < 4; i++) {
        int ge = e0 + tr; if (ge >= NE) ge = NE - 1;
        int gi = tg ^ (tr & 7);
        GLOAD_LDS16(qbuf + (long long)ge * 256 + i * 64 + gi * 8,
                    Qs + i * 4096 + wave * 512);
    }
#pragma unroll
    for (int j = 0; j < 8; j++) {
        int n  = j * 64 + tr;
        int gi = tg ^ (n & 7);
        GLOAD_LDS16(kbuf + (long long)(b * 512 + n) * 256 + gi * 8,
                    Ks + j * 4096 + wave * 512);
    }
    int mk[4];
#pragma unroll
    for (int nf = 0; nf < 4; nf++) mk[nf] = mask[b * 512 + wave * 64 + nf * 16 + fr];

    f32x4 acc[4][4];
#pragma unroll
    for (int i = 0; i < 4; i++)
#pragma unroll
        for (int j = 0; j < 4; j++) acc[i][j] = (f32x4)0.f;

    __syncthreads();

    for (int ks = 0; ks < 4; ks++) {
#pragma unroll
        for (int h = 0; h < 2; h++) {
            bf16x8 af[4], bv[4];
#pragma unroll
            for (int mf = 0; mf < 4; mf++) {
                int e = mf * 16 + fr;
                int byo = ks * 8192 + e * 128 + ((h * 64 + fq * 16) ^ ((e & 7) << 4));
                af[mf] = *(const bf16x8*)((const char*)Qs + byo);
            }
#pragma unroll
            for (int nf = 0; nf < 4; nf++) {
                int n = wave * 64 + nf * 16 + fr;
                int byo = n * 128 + ((h * 64 + fq * 16) ^ ((n & 7) << 4));
                bv[nf] = *(const bf16x8*)((const char*)Ks + byo);
            }
#pragma unroll
            for (int mf = 0; mf < 4; mf++)
#pragma unroll
                for (int nf = 0; nf < 4; nf++)
                    acc[mf][nf] = __builtin_amdgcn_mfma_f32_16x16x32_bf16(
                        af[mf], bv[nf], acc[mf][nf], 0, 0, 0);
        }
        if (ks < 3) {
            __syncthreads();
#pragma unroll
            for (int j = 0; j < 8; j++) {
                int n  = j * 64 + tr;
                int gi = tg ^ (n & 7);
                GLOAD_LDS16(kbuf + (long long)(b * 512 + n) * 256 + (ks + 1) * 64 + gi * 8,
                            Ks + j * 4096 + wave * 512);
            }
            __syncthreads();
        }
    }

    const float scale = 0.0625f;
#pragma unroll
    for (int mf = 0; mf < 4; mf++)
#pragma unroll
        for (int nf = 0; nf < 4; nf++)
#pragma unroll
            for (int r = 0; r < 4; r++)
                acc[mf][nf][r] = mk[nf] ? acc[mf][nf][r] * scale : -1e9f;

    float gm[4][4];
#pragma unroll
    for (int mf = 0; mf < 4; mf++)
#pragma unroll
        for (int r = 0; r < 4; r++) {
            float m = fmaxf(fmaxf(acc[mf][0][r], acc[mf][1][r]),
                            fmaxf(acc[mf][2][r], acc[mf][3][r]));
#pragma unroll
            for (int off = 1; off < 16; off <<= 1) m = fmaxf(m, __shfl_xor(m, off, 64));
            if (fr == 0) red[(mf * 16 + fq * 4 + r) * 8 + wave] = m;
        }
    __syncthreads();
#pragma unroll
    for (int mf = 0; mf < 4; mf++)
#pragma unroll
        for (int r = 0; r < 4; r++) {
            int row = mf * 16 + fq * 4 + r;
            float4 a = *(float4*)&red[row * 8];
            float4 c = *(float4*)&red[row * 8 + 4];
            gm[mf][r] = fmaxf(fmaxf(fmaxf(a.x, a.y), fmaxf(a.z, a.w)),
                              fmaxf(fmaxf(c.x, c.y), fmaxf(c.z, c.w)));
        }
    __syncthreads();

    float inv[4][4];
#pragma unroll
    for (int mf = 0; mf < 4; mf++)
#pragma unroll
        for (int r = 0; r < 4; r++) {
            float s = 0.f;
#pragma unroll
            for (int nf = 0; nf < 4; nf++) {
                acc[mf][nf][r] = __expf(acc[mf][nf][r] - gm[mf][r]);
                s += acc[mf][nf][r];
            }
#pragma unroll
            for (int off = 1; off < 16; off <<= 1) s += __shfl_xor(s, off, 64);
            if (fr == 0) red[(mf * 16 + fq * 4 + r) * 8 + wave] = s;
        }
    __syncthreads();
#pragma unroll
    for (int mf = 0; mf < 4; mf++)
#pragma unroll
        for (int r = 0; r < 4; r++) {
            int row = mf * 16 + fq * 4 + r;
            float4 a = *(float4*)&red[row * 8];
            float4 c = *(float4*)&red[row * 8 + 4];
            inv[mf][r] = 1.f / (a.x + a.y + a.z + a.w + c.x + c.y + c.z + c.w);
        }

#pragma unroll
    for (int mf = 0; mf < 4; mf++)
#pragma unroll
        for (int nf = 0; nf < 4; nf++)
#pragma unroll
            for (int r = 0; r < 4; r++) {
                int row = mf * 16 + fq * 4 + r;
                int c   = wave * 64 + nf * 16 + fr;
                float pv = mk[nf] ? acc[mf][nf][r] * inv[mf][r] : 0.f;
                *(unsigned short*)((char*)Ps + row * 1024 + ((c * 2) ^ ((row & 7) << 4))) =
                    f2bf(pv);
            }
    __syncthreads();

    f32x4 acc2[4][2];
#pragma unroll
    for (int i = 0; i < 4; i++)
#pragma unroll
        for (int j = 0; j < 2; j++) acc2[i][j] = (f32x4)0.f;

#pragma unroll
    for (int j = 0; j < 4; j++) {
        int l  = j * 64 + tr;
        int gi = tg ^ (l & 7);
        GLOAD_LDS16(vt + (long long)(b * 256 + l) * 512 + gi * 8,
                    Vs + j * 4096 + wave * 512);
    }
    __syncthreads();

    for (int ks = 0; ks < 8; ks++) {
#pragma unroll
        for (int h = 0; h < 2; h++) {
            bf16x8 af[4], bv[2];
#pragma unroll
            for (int mf = 0; mf < 4; mf++) {
                int e = mf * 16 + fr;
                int byo = e * 1024 + ((ks * 128 + h * 64 + fq * 16) ^ ((e & 7) << 4));
                af[mf] = *(const bf16x8*)((const char*)Ps + byo);
            }
#pragma unroll
            for (int nf = 0; nf < 2; nf++) {
                int l = wave * 32 + nf * 16 + fr;
                int byo = l * 128 + ((h * 64 + fq * 16) ^ ((l & 7) << 4));
                bv[nf] = *(const bf16x8*)((const char*)Vs + byo);
            }
#pragma unroll
            for (int mf = 0; mf < 4; mf++)
#pragma unroll
                for (int nf = 0; nf < 2; nf++)
                    acc2[mf][nf] = __builtin_amdgcn_mfma_f32_16x16x32_bf16(
                        af[mf], bv[nf], acc2[mf][nf], 0, 0, 0);
        }
        if (ks < 7) {
            __syncthreads();
#pragma unroll
            for (int j = 0; j < 4; j++) {
                int l  = j * 64 + tr;
                int gi = tg ^ (l & 7);
                GLOAD_LDS16(vt + (long long)(b * 256 + l) * 512 + (ks + 1) * 64 + gi * 8,
                            Vs + j * 4096 + wave * 512);
            }
            __syncthreads();
        }
    }

    // ---- o-MLP phase: stage [64 e][256] into LDS (swizzled), run 2 layers ----
    __syncthreads();   // PV reads of Ps/Vs complete
#pragma unroll
    for (int mf = 0; mf < 4; mf++)
#pragma unroll
        for (int nf = 0; nf < 2; nf++)
#pragma unroll
            for (int r = 0; r < 4; r++) {
                int row = mf * 16 + fq * 4 + r;              // e-local
                int col = wave * 32 + nf * 16 + fr;          // latent
                *(unsigned short*)((char*)oin + row * 512 +
                                   ((col * 2) ^ ((row & 7) << 4))) =
                    f2bf(acc2[mf][nf][r]);
            }
    __syncthreads();

    mlp_layer_io<256, true>(wt + OW1, ob1, oin, obuf, wave, lane, fr, fq);
    f32x4 oacc[2][4];
    mlp_final512(wt + OW2, ob2, obuf, wave, lane, fr, fq, oacc);

#pragma unroll
    for (int mf = 0; mf < 2; mf++)
#pragma unroll
        for (int nf = 0; nf < 4; nf++) {
            int e = e0 + nf * 16 + fr;
            if (e < NE)
                *reinterpret_cast<f32x4*>(
                    out + ((long long)b * NE + e) * 256 + wave * 32 + mf * 16 + fq * 4) =
                    oacc[mf][nf];
        }
}

// ---------------------------------------------------------------------------
__global__ __launch_bounds__(256) void f32_to_bf16(
    const float* __restrict__ in, unsigned short* __restrict__ out, long long n8)
{
    long long i      = (long long)blockIdx.x * 256 + threadIdx.x;
    long long stride = (long long)gridDim.x * 256;
    for (; i < n8; i += stride) {
        const float4* p = reinterpret_cast<const float4*>(in + i * 8);
        float4 a = p[0], b = p[1];
        u16x8 o;
        o[0] = f2bf(a.x); o[1] = f2bf(a.y); o[2] = f2bf(a.z); o[3] = f2bf(a.w);
        o[4] = f2bf(b.x); o[5] = f2bf(b.y); o[6] = f2bf(b.z); o[7] = f2bf(b.w);
        *reinterpret_cast<u16x8*>(out + i * 8) = o;
    }
}

// ---------------------------------------------------------------------------
// 11 weights W[K,N] fp32 -> packed bf16 fragment order:
//   element [f16*16+fr][ks*32+fq*8+e]  ->  Od + ((f16*(K/32)+ks)*64+fq*16+fr)*8+e
// ---------------------------------------------------------------------------
__global__ __launch_bounds__(256) void wt_pack(
    const float* w0, const float* w1, const float* w2, const float* w3,
    const float* w4, const float* w5, const float* w6, const float* w7,
    const float* w8, const float* w9, const float* w10, unsigned short* dst)
{
    const int Kd[11] = {64, 512, 512, 256, 512, 512, 256, 512, 512, 256, 512};
    const int Nd[11] = {512, 512, 256, 512, 512, 256, 512, 512, 256, 512, 256};
    const long long Od[11] = {QW1, QW2, QW3, KW1, KW2, KW3, VW1, VW2, VW3, OW1, OW2};
    const int z = blockIdx.z;
    const float* src = z == 0 ? w0 : z == 1 ? w1 : z == 2 ? w2 : z == 3 ? w3 :
                       z == 4 ? w4 : z == 5 ? w5 : z == 6 ? w6 : z == 7 ? w7 :
                       z == 8 ? w8 : z == 9 ? w9 : w10;
    const int K = Kd[z], N = Nd[z];
    const int k0 = blockIdx.y * 64, n0 = blockIdx.x * 64;
    if (k0 >= K || n0 >= N) return;

    __shared__ float tf[64][65];
    const int t = threadIdx.x;
    {
        const int r = t >> 2;
        const int c0 = (t & 3) * 16;
        const float* srow = src + (long long)(k0 + r) * N + n0 + c0;
#pragma unroll
        for (int q = 0; q < 4; q++) {
            float4 xv = *reinterpret_cast<const float4*>(srow + q * 4);
            tf[r][c0 + q * 4 + 0] = xv.x;
            tf[r][c0 + q * 4 + 1] = xv.y;
            tf[r][c0 + q * 4 + 2] = xv.z;
            tf[r][c0 + q * 4 + 3] = xv.w;
        }
    }
    __syncthreads();

#pragma unroll
    for (int it = 0; it < 2; it++) {
        int wi = t + it * 256;
        int nc = wi & 63;
        int k8 = wi >> 6;
        int kg = k0 + k8 * 8;
        int ks = kg >> 5;
        int fq = (kg >> 3) & 3;
        int f16 = (n0 + nc) >> 4;
        int fr  = nc & 15;
        u16x8 ov;
#pragma unroll
        for (int e = 0; e < 8; e++) ov[e] = f2bf(tf[k8 * 8 + e][nc]);
        long long off = Od[z] +
            (((long long)f16 * (K / 32) + ks) * 64 + fq * 16 + fr) * 8;
        *reinterpret_cast<u16x8*>(dst + off) = ov;
    }
}

// ---------------------------------------------------------------------------
extern "C" void kernel_launch(void* const* d_in, const int* in_sizes, int n_in,
                              void* d_out, int out_size, void* d_ws, size_t ws_size,
                              hipStream_t stream)
{
    const float* field = (const float*)d_in[0];   // [64,512,256]
    const int*   mask  = (const int*)d_in[1];     // [64,512]
    const float* efeat = (const float*)d_in[2];   // [500,64]
    const float* q_w1 = (const float*)d_in[3];  const float* q_b1 = (const float*)d_in[4];
    const float* q_w2 = (const float*)d_in[5];  const float* q_b2 = (const float*)d_in[6];
    const float* q_w3 = (const float*)d_in[7];  const float* q_b3 = (const float*)d_in[8];
    const float* k_w1 = (const float*)d_in[9];  const float* k_b1 = (const float*)d_in[10];
    const float* k_w2 = (const float*)d_in[11]; const float* k_b2 = (const float*)d_in[12];
    const float* k_w3 = (const float*)d_in[13]; const float* k_b3 = (const float*)d_in[14];
    const float* v_w1 = (const float*)d_in[15]; const float* v_b1 = (const float*)d_in[16];
    const float* v_w2 = (const float*)d_in[17]; const float* v_b2 = (const float*)d_in[18];
    const float* v_w3 = (const float*)d_in[19]; const float* v_b3 = (const float*)d_in[20];
    const float* o_w1 = (const float*)d_in[21]; const float* o_b1 = (const float*)d_in[22];
    const float* o_w2 = (const float*)d_in[23]; const float* o_b2 = (const float*)d_in[24];

    // workspace (ushort units)
    unsigned short* ws = (unsigned short*)d_ws;
    unsigned short* field_bf = ws;                 // 8,388,608
    unsigned short* efeat_bf = ws + 8388608;       // 32,000
    unsigned short* wt       = ws + 8420608;       // 1,736,704
    unsigned short* qbuf     = ws + 10157312;      // 128,000
    unsigned short* kbuf     = ws + 10285312;      // 8,388,608
    unsigned short* vtb      = ws + 18673920;      // 8,388,608

    // conversions + packed weight transform
    f32_to_bf16<<<dim3(2048), dim3(256), 0, stream>>>(field, field_bf, 1048576);
    f32_to_bf16<<<dim3(16),   dim3(256), 0, stream>>>(efeat, efeat_bf, 4000);
    wt_pack<<<dim3(8, 8, 11), dim3(256), 0, stream>>>(
        q_w1, q_w2, q_w3, k_w1, k_w2, k_w3, v_w1, v_w2, v_w3, o_w1, o_w2, wt);

    // q + k + v MLPs (2064 blocks x 512 threads, 32 rows/block, 4 blocks/CU)
    fused_qkv<<<dim3(2064), dim3(512), 0, stream>>>(
        field_bf, efeat_bf, wt, q_b1, q_b2, q_b3, k_b1, k_b2, k_b3,
        v_b1, v_b2, v_b3, qbuf, kbuf, vtb);

    // fused attention + o-MLP (stores f32 output directly)
    attn_fused<<<dim3(512), dim3(512), 0, stream>>>(
        qbuf, kbuf, vtb, mask, wt, o_b1, o_b2, (float*)d_out);
}

// Round 20
// 198.435 us; speedup vs baseline: 1.0050x; 1.0050x over previous
//
#include <hip/hip_runtime.h>
#include <math.h>

// Problem constants
#define BATCH 64
#define N_ATOMS 512
#define NE 500
#define FIELD_DIM 256
#define E_DIM 64
#define HIDDEN 512
#define LATENT 256

typedef short bf16x8 __attribute__((ext_vector_type(8)));
typedef unsigned short u16x8 __attribute__((ext_vector_type(8)));
typedef unsigned short u16x4 __attribute__((ext_vector_type(4)));
typedef float f32x4 __attribute__((ext_vector_type(4)));

__device__ __forceinline__ unsigned short f2bf(float x) {
    unsigned u = __float_as_uint(x);
    unsigned r = (u + 0x7FFFu + ((u >> 16) & 1u)) >> 16;
    return (unsigned short)r;
}
__device__ __forceinline__ float bf2f(unsigned short b) {
    return __uint_as_float(((unsigned)b) << 16);
}
__device__ __forceinline__ float silu_f(float x) { return x / (1.f + __expf(-x)); }

#define GLOAD_LDS16(gptr, lptr)                                                   \
    __builtin_amdgcn_global_load_lds(                                             \
        (const __attribute__((address_space(1))) void*)(gptr),                    \
        (__attribute__((address_space(3))) void*)(lptr), 16, 0, 0)

// weight offsets inside wt (ushort units), order q1,q2,q3,k1,k2,k3,v1,v2,v3,o1,o2
#define QW1 0
#define QW2 32768
#define QW3 294912
#define KW1 425984
#define KW2 557056
#define KW3 819200
#define VW1 950272
#define VW2 1081344
#define VW3 1343488
#define OW1 1474560
#define OW2 1605632

// ===========================================================================
// 32-ROW in-place MLP layer for fused_qkv (32KB LDS, 3 blocks/CU — measured
// best, r18). 8 waves; wave computes 64 features over 32 rows (nf<2).
// Packed weights: (( (wave*4+mf)*NS + ks)*64 + lane)*8. Depth-1 prefetch.
// D mapping (validated r4-r19): feature = fq*4+r, act-row = fr.
// ===========================================================================
template <int K, bool SILU>
__device__ __forceinline__ void mlp_layer_ip32(
    const unsigned short* __restrict__ Wg, const float* __restrict__ Bg,
    unsigned short* buf, int wave, int lane, int fr, int fq)
{
    constexpr int NS = K / 32;
    const int fb = wave * 64;
    const unsigned short* wp = Wg + (long long)(wave * 4) * NS * 512 + lane * 8;

    f32x4 acc[4][2];
#pragma unroll
    for (int mf = 0; mf < 4; mf++)
#pragma unroll
        for (int nf = 0; nf < 2; nf++) acc[mf][nf] = (f32x4)0.f;

    bf16x8 wfA[4];
#pragma unroll
    for (int mf = 0; mf < 4; mf++)
        wfA[mf] = *reinterpret_cast<const bf16x8*>(wp + (long long)mf * NS * 512);

#pragma unroll
    for (int ks = 0; ks < NS; ks++) {
        bf16x8 wfB[4];
        if (ks + 1 < NS) {
#pragma unroll
            for (int mf = 0; mf < 4; mf++)
                wfB[mf] = *reinterpret_cast<const bf16x8*>(
                    wp + ((long long)mf * NS + (ks + 1)) * 512);
        }
        bf16x8 bfr[2];
#pragma unroll
        for (int nf = 0; nf < 2; nf++) {
            int row = nf * 16 + fr;
            bfr[nf] = *reinterpret_cast<const bf16x8*>(
                (const char*)buf + row * (K * 2) +
                ((ks * 64 + fq * 16) ^ ((row & 7) << 4)));
        }
        __builtin_amdgcn_s_setprio(1);
#pragma unroll
        for (int mf = 0; mf < 4; mf++)
#pragma unroll
            for (int nf = 0; nf < 2; nf++)
                acc[mf][nf] = __builtin_amdgcn_mfma_f32_16x16x32_bf16(
                    wfA[mf], bfr[nf], acc[mf][nf], 0, 0, 0);
        __builtin_amdgcn_s_setprio(0);
        if (ks + 1 < NS) {
#pragma unroll
            for (int mf = 0; mf < 4; mf++) wfA[mf] = wfB[mf];
        }
    }
    __syncthreads();   // all reads complete before in-place overwrite

#pragma unroll
    for (int mf = 0; mf < 4; mf++) {
        f32x4 bv = *reinterpret_cast<const f32x4*>(Bg + fb + mf * 16 + fq * 4);
#pragma unroll
        for (int nf = 0; nf < 2; nf++) {
            int row = nf * 16 + fr;
            u16x4 ov;
#pragma unroll
            for (int r = 0; r < 4; r++) {
                float x = acc[mf][nf][r] + bv[r];
                if (SILU) x = silu_f(x);
                ov[r] = f2bf(x);
            }
            *reinterpret_cast<u16x4*>(
                (char*)buf + row * 1024 +
                ((fb * 2 + mf * 32 + fq * 8) ^ ((row & 7) << 4))) = ov;
        }
    }
    __syncthreads();
}

// 32-row final layer: [32][512] -> 256 features (wave does 32), acc[2][2]
__device__ __forceinline__ void mlp_final32(
    const unsigned short* __restrict__ Wg, const float* __restrict__ Bg,
    const unsigned short* buf, int wave, int lane, int fr, int fq,
    f32x4 (&acc)[2][2])
{
    const int fb = wave * 32;
    const unsigned short* wp = Wg + (long long)(wave * 2) * 16 * 512 + lane * 8;
#pragma unroll
    for (int mf = 0; mf < 2; mf++)
#pragma unroll
        for (int nf = 0; nf < 2; nf++) acc[mf][nf] = (f32x4)0.f;

    bf16x8 wfA[2];
#pragma unroll
    for (int mf = 0; mf < 2; mf++)
        wfA[mf] = *reinterpret_cast<const bf16x8*>(wp + (long long)mf * 16 * 512);

#pragma unroll
    for (int ks = 0; ks < 16; ks++) {
        bf16x8 wfB[2];
        if (ks + 1 < 16) {
#pragma unroll
            for (int mf = 0; mf < 2; mf++)
                wfB[mf] = *reinterpret_cast<const bf16x8*>(
                    wp + ((long long)mf * 16 + (ks + 1)) * 512);
        }
        bf16x8 bfr[2];
#pragma unroll
        for (int nf = 0; nf < 2; nf++) {
            int row = nf * 16 + fr;
            bfr[nf] = *reinterpret_cast<const bf16x8*>(
                (const char*)buf + row * 1024 +
                ((ks * 64 + fq * 16) ^ ((row & 7) << 4)));
        }
        __builtin_amdgcn_s_setprio(1);
#pragma unroll
        for (int mf = 0; mf < 2; mf++)
#pragma unroll
            for (int nf = 0; nf < 2; nf++)
                acc[mf][nf] = __builtin_amdgcn_mfma_f32_16x16x32_bf16(
                    wfA[mf], bfr[nf], acc[mf][nf], 0, 0, 0);
        __builtin_amdgcn_s_setprio(0);
        if (ks + 1 < 16) {
#pragma unroll
            for (int mf = 0; mf < 2; mf++) wfA[mf] = wfB[mf];
        }
    }
#pragma unroll
    for (int mf = 0; mf < 2; mf++) {
        f32x4 bv = *reinterpret_cast<const f32x4*>(Bg + fb + mf * 16 + fq * 4);
#pragma unroll
        for (int nf = 0; nf < 2; nf++)
#pragma unroll
            for (int r = 0; r < 4; r++) acc[mf][nf][r] += bv[r];
    }
}

// ===========================================================================
// 64-row helpers (r13, unchanged) for the attn o-phase.
// ===========================================================================
template <int K, bool SILU>
__device__ __forceinline__ void mlp_layer_io(
    const unsigned short* __restrict__ Wg, const float* __restrict__ Bg,
    const unsigned short* inb, unsigned short* outb, int wave, int lane,
    int fr, int fq)
{
    constexpr int NS = K / 32;
    const int fb = wave * 64;
    const unsigned short* wp = Wg + (long long)(wave * 4) * NS * 512 + lane * 8;

    f32x4 acc[4][4];
#pragma unroll
    for (int mf = 0; mf < 4; mf++)
#pragma unroll
        for (int nf = 0; nf < 4; nf++) acc[mf][nf] = (f32x4)0.f;

    bf16x8 wfA[4];
#pragma unroll
    for (int mf = 0; mf < 4; mf++)
        wfA[mf] = *reinterpret_cast<const bf16x8*>(wp + (long long)mf * NS * 512);

#pragma unroll
    for (int ks = 0; ks < NS; ks++) {
        bf16x8 wfB[4];
        if (ks + 1 < NS) {
#pragma unroll
            for (int mf = 0; mf < 4; mf++)
                wfB[mf] = *reinterpret_cast<const bf16x8*>(
                    wp + ((long long)mf * NS + (ks + 1)) * 512);
        }
        bf16x8 bfr[4];
#pragma unroll
        for (int nf = 0; nf < 4; nf++) {
            int row = nf * 16 + fr;
            bfr[nf] = *reinterpret_cast<const bf16x8*>(
                (const char*)inb + row * (K * 2) +
                ((ks * 64 + fq * 16) ^ ((row & 7) << 4)));
        }
        __builtin_amdgcn_s_setprio(1);
#pragma unroll
        for (int mf = 0; mf < 4; mf++)
#pragma unroll
            for (int nf = 0; nf < 4; nf++)
                acc[mf][nf] = __builtin_amdgcn_mfma_f32_16x16x32_bf16(
                    wfA[mf], bfr[nf], acc[mf][nf], 0, 0, 0);
        __builtin_amdgcn_s_setprio(0);
        if (ks + 1 < NS) {
#pragma unroll
            for (int mf = 0; mf < 4; mf++) wfA[mf] = wfB[mf];
        }
    }

#pragma unroll
    for (int mf = 0; mf < 4; mf++) {
        f32x4 bv = *reinterpret_cast<const f32x4*>(Bg + fb + mf * 16 + fq * 4);
#pragma unroll
        for (int nf = 0; nf < 4; nf++) {
            int row = nf * 16 + fr;
            u16x4 ov;
#pragma unroll
            for (int r = 0; r < 4; r++) {
                float x = acc[mf][nf][r] + bv[r];
                if (SILU) x = silu_f(x);
                ov[r] = f2bf(x);
            }
            *reinterpret_cast<u16x4*>(
                (char*)outb + row * 1024 +
                ((fb * 2 + mf * 32 + fq * 8) ^ ((row & 7) << 4))) = ov;
        }
    }
    __syncthreads();
}

__device__ __forceinline__ void mlp_final512(
    const unsigned short* __restrict__ Wg, const float* __restrict__ Bg,
    const unsigned short* buf, int wave, int lane, int fr, int fq,
    f32x4 (&acc)[2][4])
{
    const int fb = wave * 32;
    const unsigned short* wp = Wg + (long long)(wave * 2) * 16 * 512 + lane * 8;
#pragma unroll
    for (int mf = 0; mf < 2; mf++)
#pragma unroll
        for (int nf = 0; nf < 4; nf++) acc[mf][nf] = (f32x4)0.f;

    bf16x8 wfA[2];
#pragma unroll
    for (int mf = 0; mf < 2; mf++)
        wfA[mf] = *reinterpret_cast<const bf16x8*>(wp + (long long)mf * 16 * 512);

#pragma unroll
    for (int ks = 0; ks < 16; ks++) {
        bf16x8 wfB[2];
        if (ks + 1 < 16) {
#pragma unroll
            for (int mf = 0; mf < 2; mf++)
                wfB[mf] = *reinterpret_cast<const bf16x8*>(
                    wp + ((long long)mf * 16 + (ks + 1)) * 512);
        }
        bf16x8 bfr[4];
#pragma unroll
        for (int nf = 0; nf < 4; nf++) {
            int row = nf * 16 + fr;
            bfr[nf] = *reinterpret_cast<const bf16x8*>(
                (const char*)buf + row * 1024 +
                ((ks * 64 + fq * 16) ^ ((row & 7) << 4)));
        }
        __builtin_amdgcn_s_setprio(1);
#pragma unroll
        for (int mf = 0; mf < 2; mf++)
#pragma unroll
            for (int nf = 0; nf < 4; nf++)
                acc[mf][nf] = __builtin_amdgcn_mfma_f32_16x16x32_bf16(
                    wfA[mf], bfr[nf], acc[mf][nf], 0, 0, 0);
        __builtin_amdgcn_s_setprio(0);
        if (ks + 1 < 16) {
#pragma unroll
            for (int mf = 0; mf < 2; mf++) wfA[mf] = wfB[mf];
        }
    }
#pragma unroll
    for (int mf = 0; mf < 2; mf++) {
        f32x4 bv = *reinterpret_cast<const f32x4*>(Bg + fb + mf * 16 + fq * 4);
#pragma unroll
        for (int nf = 0; nf < 4; nf++)
#pragma unroll
            for (int r = 0; r < 4; r++) acc[mf][nf][r] += bv[r];
    }
}

// ===========================================================================
// q + k + v MLPs, 32 rows/block. blocks 0-1023: k, 1024-2047: v, 2048-2063: q.
// 32KB LDS, __launch_bounds__(512,3) -> 3 blocks/CU (measured best, r18).
// ===========================================================================
__global__ __launch_bounds__(512, 3) void fused_qkv(
    const unsigned short* __restrict__ field_bf,  // [32768][256]
    const unsigned short* __restrict__ efeat_bf,  // [500][64]
    const unsigned short* __restrict__ wt,
    const float* __restrict__ qb1, const float* __restrict__ qb2,
    const float* __restrict__ qb3, const float* __restrict__ kb1,
    const float* __restrict__ kb2, const float* __restrict__ kb3,
    const float* __restrict__ vb1, const float* __restrict__ vb2,
    const float* __restrict__ vb3,
    unsigned short* __restrict__ qbuf,   // [500][256]
    unsigned short* __restrict__ kbuf,   // [32768][256]
    unsigned short* __restrict__ vtb)    // [64][256][512]
{
    __shared__ unsigned short buf[32 * 512];   // 32KB
    const int t = threadIdx.x, wave = t >> 6, lane = t & 63;
    const int fr = lane & 15, fq = lane >> 4;
    const int bid = blockIdx.x;

    if (bid < 2048) {
        const int isv = bid >> 10;
        const int m0  = (bid & 1023) * 32;
        const unsigned short* W1 = wt + (isv ? VW1 : KW1);
        const unsigned short* W2 = wt + (isv ? VW2 : KW2);
        const unsigned short* W3 = wt + (isv ? VW3 : KW3);
        const float* B1 = isv ? vb1 : kb1;
        const float* B2 = isv ? vb2 : kb2;
        const float* B3 = isv ? vb3 : kb3;

        // stage [32][256] (16KB), swizzled source
#pragma unroll
        for (int c = wave; c < 16; c += 8) {
            int gi  = c * 64 + lane;
            int row = gi >> 5;
            int g   = gi & 31;
            int gs  = (g & ~7) | ((g & 7) ^ (row & 7));
            GLOAD_LDS16(field_bf + (long long)(m0 + row) * 256 + gs * 8, buf + c * 512);
        }
        __syncthreads();

        mlp_layer_ip32<256, true>(W1, B1, buf, wave, lane, fr, fq);
        mlp_layer_ip32<512, true>(W2, B2, buf, wave, lane, fr, fq);
        f32x4 acc[2][2];
        mlp_final32(W3, B3, buf, wave, lane, fr, fq, acc);

        if (!isv) {  // k: bf16 [32768][256]
#pragma unroll
            for (int mf = 0; mf < 2; mf++)
#pragma unroll
                for (int nf = 0; nf < 2; nf++) {
                    int row = m0 + nf * 16 + fr;
                    u16x4 ov;
#pragma unroll
                    for (int r = 0; r < 4; r++) ov[r] = f2bf(acc[mf][nf][r]);
                    *reinterpret_cast<u16x4*>(
                        kbuf + (long long)row * 256 + wave * 32 + mf * 16 + fq * 4) = ov;
                }
        } else {     // v: transposed -> vtb[b][256][512]
            __syncthreads();  // final reads done before overwrite
#pragma unroll
            for (int mf = 0; mf < 2; mf++)
#pragma unroll
                for (int nf = 0; nf < 2; nf++) {
                    int row = nf * 16 + fr;
                    u16x4 ov;
#pragma unroll
                    for (int r = 0; r < 4; r++) ov[r] = f2bf(acc[mf][nf][r]);
                    *reinterpret_cast<u16x4*>(
                        (char*)buf + row * 512 +
                        ((wave * 64 + mf * 32 + fq * 8) ^ ((row & 7) << 4))) = ov;
                }
            __syncthreads();
            // transposed store: thread -> (l = t>>1, half of 32 atoms)
            int l  = t >> 1;
            int nh = (t & 1) * 16;
            int b  = m0 >> 9, nb = m0 & 511;
            long long base = ((long long)b * 256 + l) * 512 + nb + nh;
#pragma unroll
            for (int q = 0; q < 2; q++) {
                u16x8 ov;
#pragma unroll
                for (int j = 0; j < 8; j++) {
                    int n = nh + q * 8 + j;
                    ov[j] = *reinterpret_cast<const unsigned short*>(
                        (const char*)buf + n * 512 + ((l * 2) ^ ((n & 7) << 4)));
                }
                *reinterpret_cast<u16x8*>(vtb + base + q * 8) = ov;
            }
        }
    } else {  // q MLP: 16 blocks of 32 rows, M=500, K_IN=64
        const int m0 = (bid - 2048) * 32;
        // stage [32][64] (4KB): waves 0-3 only
        for (int c = wave; c < 4; c += 8) {
            int gi  = c * 64 + lane;
            int row = gi >> 3;
            int g   = gi & 7;
            int gr  = m0 + row; if (gr >= NE) gr = NE - 1;
            int gs  = g ^ (row & 7);
            GLOAD_LDS16(efeat_bf + (long long)gr * 64 + gs * 8, buf + c * 512);
        }
        __syncthreads();

        mlp_layer_ip32<64, true>(wt + QW1, qb1, buf, wave, lane, fr, fq);
        mlp_layer_ip32<512, true>(wt + QW2, qb2, buf, wave, lane, fr, fq);
        f32x4 acc[2][2];
        mlp_final32(wt + QW3, qb3, buf, wave, lane, fr, fq, acc);
#pragma unroll
        for (int mf = 0; mf < 2; mf++)
#pragma unroll
            for (int nf = 0; nf < 2; nf++) {
                int row = m0 + nf * 16 + fr;
                if (row < NE) {
                    u16x4 ov;
#pragma unroll
                    for (int r = 0; r < 4; r++) ov[r] = f2bf(acc[mf][nf][r]);
                    *reinterpret_cast<u16x4*>(
                        qbuf + (long long)row * 256 + wave * 32 + mf * 16 + fq * 4) = ov;
                }
            }
    }
}

// ---------------------------------------------------------------------------
// Fused attention + o-MLP (r13/r17 structure, unchanged).
// ---------------------------------------------------------------------------
__global__ __launch_bounds__(512, 1) void attn_fused(
    const unsigned short* __restrict__ qbuf,   // [NE][256]
    const unsigned short* __restrict__ kbuf,   // [B][512][256]
    const unsigned short* __restrict__ vt,     // [B][256][512]
    const int* __restrict__ mask,              // [B][512]
    const unsigned short* __restrict__ wt,
    const float* __restrict__ ob1, const float* __restrict__ ob2,
    float* __restrict__ out)                   // [B*NE][256] f32
{
    __shared__ unsigned char LDS[100352];
    unsigned short* Qs = (unsigned short*)LDS;             // [4][64][64] 32KB
    unsigned short* Ks = (unsigned short*)(LDS + 32768);   // [512][64]   64KB
    unsigned short* Ps = (unsigned short*)LDS;             // [64][512]   overlay
    unsigned short* Vs = (unsigned short*)(LDS + 65536);   // [256][64]   32KB
    float*          red = (float*)(LDS + 98304);           // [64][8]
    unsigned short* oin  = (unsigned short*)(LDS + 65536); // [64][256] 32KB (o-phase)
    unsigned short* obuf = (unsigned short*)LDS;           // [64][512] 64KB (o-phase)

    const int id = blockIdx.x;
    const int b  = id & 63;
    const int e0 = (id >> 6) * 64;
    const int t = threadIdx.x, wave = t >> 6;
    const int lane = t & 63, fr = lane & 15, fq = lane >> 4;
    const int tr = t >> 3, tg = t & 7;

#pragma unroll
    for (int i = 0; i < 4; i++) {
        int ge = e0 + tr; if (ge >= NE) ge = NE - 1;
        int gi = tg ^ (tr & 7);
        GLOAD_LDS16(qbuf + (long long)ge * 256 + i * 64 + gi * 8,
                    Qs + i * 4096 + wave * 512);
    }
#pragma unroll
    for (int j = 0; j < 8; j++) {
        int n  = j * 64 + tr;
        int gi = tg ^ (n & 7);
        GLOAD_LDS16(kbuf + (long long)(b * 512 + n) * 256 + gi * 8,
                    Ks + j * 4096 + wave * 512);
    }
    int mk[4];
#pragma unroll
    for (int nf = 0; nf < 4; nf++) mk[nf] = mask[b * 512 + wave * 64 + nf * 16 + fr];

    f32x4 acc[4][4];
#pragma unroll
    for (int i = 0; i < 4; i++)
#pragma unroll
        for (int j = 0; j < 4; j++) acc[i][j] = (f32x4)0.f;

    __syncthreads();

    for (int ks = 0; ks < 4; ks++) {
#pragma unroll
        for (int h = 0; h < 2; h++) {
            bf16x8 af[4], bv[4];
#pragma unroll
            for (int mf = 0; mf < 4; mf++) {
                int e = mf * 16 + fr;
                int byo = ks * 8192 + e * 128 + ((h * 64 + fq * 16) ^ ((e & 7) << 4));
                af[mf] = *(const bf16x8*)((const char*)Qs + byo);
            }
#pragma unroll
            for (int nf = 0; nf < 4; nf++) {
                int n = wave * 64 + nf * 16 + fr;
                int byo = n * 128 + ((h * 64 + fq * 16) ^ ((n & 7) << 4));
                bv[nf] = *(const bf16x8*)((const char*)Ks + byo);
            }
#pragma unroll
            for (int mf = 0; mf < 4; mf++)
#pragma unroll
                for (int nf = 0; nf < 4; nf++)
                    acc[mf][nf] = __builtin_amdgcn_mfma_f32_16x16x32_bf16(
                        af[mf], bv[nf], acc[mf][nf], 0, 0, 0);
        }
        if (ks < 3) {
            __syncthreads();
#pragma unroll
            for (int j = 0; j < 8; j++) {
                int n  = j * 64 + tr;
                int gi = tg ^ (n & 7);
                GLOAD_LDS16(kbuf + (long long)(b * 512 + n) * 256 + (ks + 1) * 64 + gi * 8,
                            Ks + j * 4096 + wave * 512);
            }
            __syncthreads();
        }
    }

    const float scale = 0.0625f;
#pragma unroll
    for (int mf = 0; mf < 4; mf++)
#pragma unroll
        for (int nf = 0; nf < 4; nf++)
#pragma unroll
            for (int r = 0; r < 4; r++)
                acc[mf][nf][r] = mk[nf] ? acc[mf][nf][r] * scale : -1e9f;

    float gm[4][4];
#pragma unroll
    for (int mf = 0; mf < 4; mf++)
#pragma unroll
        for (int r = 0; r < 4; r++) {
            float m = fmaxf(fmaxf(acc[mf][0][r], acc[mf][1][r]),
                            fmaxf(acc[mf][2][r], acc[mf][3][r]));
#pragma unroll
            for (int off = 1; off < 16; off <<= 1) m = fmaxf(m, __shfl_xor(m, off, 64));
            if (fr == 0) red[(mf * 16 + fq * 4 + r) * 8 + wave] = m;
        }
    __syncthreads();
#pragma unroll
    for (int mf = 0; mf < 4; mf++)
#pragma unroll
        for (int r = 0; r < 4; r++) {
            int row = mf * 16 + fq * 4 + r;
            float4 a = *(float4*)&red[row * 8];
            float4 c = *(float4*)&red[row * 8 + 4];
            gm[mf][r] = fmaxf(fmaxf(fmaxf(a.x, a.y), fmaxf(a.z, a.w)),
                              fmaxf(fmaxf(c.x, c.y), fmaxf(c.z, c.w)));
        }
    __syncthreads();

    float inv[4][4];
#pragma unroll
    for (int mf = 0; mf < 4; mf++)
#pragma unroll
        for (int r = 0; r < 4; r++) {
            float s = 0.f;
#pragma unroll
            for (int nf = 0; nf < 4; nf++) {
                acc[mf][nf][r] = __expf(acc[mf][nf][r] - gm[mf][r]);
                s += acc[mf][nf][r];
            }
#pragma unroll
            for (int off = 1; off < 16; off <<= 1) s += __shfl_xor(s, off, 64);
            if (fr == 0) red[(mf * 16 + fq * 4 + r) * 8 + wave] = s;
        }
    __syncthreads();
#pragma unroll
    for (int mf = 0; mf < 4; mf++)
#pragma unroll
        for (int r = 0; r < 4; r++) {
            int row = mf * 16 + fq * 4 + r;
            float4 a = *(float4*)&red[row * 8];
            float4 c = *(float4*)&red[row * 8 + 4];
            inv[mf][r] = 1.f / (a.x + a.y + a.z + a.w + c.x + c.y + c.z + c.w);
        }

#pragma unroll
    for (int mf = 0; mf < 4; mf++)
#pragma unroll
        for (int nf = 0; nf < 4; nf++)
#pragma unroll
            for (int r = 0; r < 4; r++) {
                int row = mf * 16 + fq * 4 + r;
                int c   = wave * 64 + nf * 16 + fr;
                float pv = mk[nf] ? acc[mf][nf][r] * inv[mf][r] : 0.f;
                *(unsigned short*)((char*)Ps + row * 1024 + ((c * 2) ^ ((row & 7) << 4))) =
                    f2bf(pv);
            }
    __syncthreads();

    f32x4 acc2[4][2];
#pragma unroll
    for (int i = 0; i < 4; i++)
#pragma unroll
        for (int j = 0; j < 2; j++) acc2[i][j] = (f32x4)0.f;

#pragma unroll
    for (int j = 0; j < 4; j++) {
        int l  = j * 64 + tr;
        int gi = tg ^ (l & 7);
        GLOAD_LDS16(vt + (long long)(b * 256 + l) * 512 + gi * 8,
                    Vs + j * 4096 + wave * 512);
    }
    __syncthreads();

    for (int ks = 0; ks < 8; ks++) {
#pragma unroll
        for (int h = 0; h < 2; h++) {
            bf16x8 af[4], bv[2];
#pragma unroll
            for (int mf = 0; mf < 4; mf++) {
                int e = mf * 16 + fr;
                int byo = e * 1024 + ((ks * 128 + h * 64 + fq * 16) ^ ((e & 7) << 4));
                af[mf] = *(const bf16x8*)((const char*)Ps + byo);
            }
#pragma unroll
            for (int nf = 0; nf < 2; nf++) {
                int l = wave * 32 + nf * 16 + fr;
                int byo = l * 128 + ((h * 64 + fq * 16) ^ ((l & 7) << 4));
                bv[nf] = *(const bf16x8*)((const char*)Vs + byo);
            }
#pragma unroll
            for (int mf = 0; mf < 4; mf++)
#pragma unroll
                for (int nf = 0; nf < 2; nf++)
                    acc2[mf][nf] = __builtin_amdgcn_mfma_f32_16x16x32_bf16(
                        af[mf], bv[nf], acc2[mf][nf], 0, 0, 0);
        }
        if (ks < 7) {
            __syncthreads();
#pragma unroll
            for (int j = 0; j < 4; j++) {
                int l  = j * 64 + tr;
                int gi = tg ^ (l & 7);
                GLOAD_LDS16(vt + (long long)(b * 256 + l) * 512 + (ks + 1) * 64 + gi * 8,
                            Vs + j * 4096 + wave * 512);
            }
            __syncthreads();
        }
    }

    // ---- o-MLP phase: stage [64 e][256] into LDS (swizzled), run 2 layers ----
    __syncthreads();   // PV reads of Ps/Vs complete
#pragma unroll
    for (int mf = 0; mf < 4; mf++)
#pragma unroll
        for (int nf = 0; nf < 2; nf++)
#pragma unroll
            for (int r = 0; r < 4; r++) {
                int row = mf * 16 + fq * 4 + r;              // e-local
                int col = wave * 32 + nf * 16 + fr;          // latent
                *(unsigned short*)((char*)oin + row * 512 +
                                   ((col * 2) ^ ((row & 7) << 4))) =
                    f2bf(acc2[mf][nf][r]);
            }
    __syncthreads();

    mlp_layer_io<256, true>(wt + OW1, ob1, oin, obuf, wave, lane, fr, fq);
    f32x4 oacc[2][4];
    mlp_final512(wt + OW2, ob2, obuf, wave, lane, fr, fq, oacc);

#pragma unroll
    for (int mf = 0; mf < 2; mf++)
#pragma unroll
        for (int nf = 0; nf < 4; nf++) {
            int e = e0 + nf * 16 + fr;
            if (e < NE)
                *reinterpret_cast<f32x4*>(
                    out + ((long long)b * NE + e) * 256 + wave * 32 + mf * 16 + fq * 4) =
                    oacc[mf][nf];
        }
}

// ---------------------------------------------------------------------------
__global__ __launch_bounds__(256) void f32_to_bf16(
    const float* __restrict__ in, unsigned short* __restrict__ out, long long n8)
{
    long long i      = (long long)blockIdx.x * 256 + threadIdx.x;
    long long stride = (long long)gridDim.x * 256;
    for (; i < n8; i += stride) {
        const float4* p = reinterpret_cast<const float4*>(in + i * 8);
        float4 a = p[0], b = p[1];
        u16x8 o;
        o[0] = f2bf(a.x); o[1] = f2bf(a.y); o[2] = f2bf(a.z); o[3] = f2bf(a.w);
        o[4] = f2bf(b.x); o[5] = f2bf(b.y); o[6] = f2bf(b.z); o[7] = f2bf(b.w);
        *reinterpret_cast<u16x8*>(out + i * 8) = o;
    }
}

// ---------------------------------------------------------------------------
// 11 weights W[K,N] fp32 -> packed bf16 fragment order:
//   element [f16*16+fr][ks*32+fq*8+e]  ->  Od + ((f16*(K/32)+ks)*64+fq*16+fr)*8+e
// ---------------------------------------------------------------------------
__global__ __launch_bounds__(256) void wt_pack(
    const float* w0, const float* w1, const float* w2, const float* w3,
    const float* w4, const float* w5, const float* w6, const float* w7,
    const float* w8, const float* w9, const float* w10, unsigned short* dst)
{
    const int Kd[11] = {64, 512, 512, 256, 512, 512, 256, 512, 512, 256, 512};
    const int Nd[11] = {512, 512, 256, 512, 512, 256, 512, 512, 256, 512, 256};
    const long long Od[11] = {QW1, QW2, QW3, KW1, KW2, KW3, VW1, VW2, VW3, OW1, OW2};
    const int z = blockIdx.z;
    const float* src = z == 0 ? w0 : z == 1 ? w1 : z == 2 ? w2 : z == 3 ? w3 :
                       z == 4 ? w4 : z == 5 ? w5 : z == 6 ? w6 : z == 7 ? w7 :
                       z == 8 ? w8 : z == 9 ? w9 : w10;
    const int K = Kd[z], N = Nd[z];
    const int k0 = blockIdx.y * 64, n0 = blockIdx.x * 64;
    if (k0 >= K || n0 >= N) return;

    __shared__ float tf[64][65];
    const int t = threadIdx.x;
    {
        const int r = t >> 2;
        const int c0 = (t & 3) * 16;
        const float* srow = src + (long long)(k0 + r) * N + n0 + c0;
#pragma unroll
        for (int q = 0; q < 4; q++) {
            float4 xv = *reinterpret_cast<const float4*>(srow + q * 4);
            tf[r][c0 + q * 4 + 0] = xv.x;
            tf[r][c0 + q * 4 + 1] = xv.y;
            tf[r][c0 + q * 4 + 2] = xv.z;
            tf[r][c0 + q * 4 + 3] = xv.w;
        }
    }
    __syncthreads();

#pragma unroll
    for (int it = 0; it < 2; it++) {
        int wi = t + it * 256;
        int nc = wi & 63;
        int k8 = wi >> 6;
        int kg = k0 + k8 * 8;
        int ks = kg >> 5;
        int fq = (kg >> 3) & 3;
        int f16 = (n0 + nc) >> 4;
        int fr  = nc & 15;
        u16x8 ov;
#pragma unroll
        for (int e = 0; e < 8; e++) ov[e] = f2bf(tf[k8 * 8 + e][nc]);
        long long off = Od[z] +
            (((long long)f16 * (K / 32) + ks) * 64 + fq * 16 + fr) * 8;
        *reinterpret_cast<u16x8*>(dst + off) = ov;
    }
}

// ---------------------------------------------------------------------------
extern "C" void kernel_launch(void* const* d_in, const int* in_sizes, int n_in,
                              void* d_out, int out_size, void* d_ws, size_t ws_size,
                              hipStream_t stream)
{
    const float* field = (const float*)d_in[0];   // [64,512,256]
    const int*   mask  = (const int*)d_in[1];     // [64,512]
    const float* efeat = (const float*)d_in[2];   // [500,64]
    const float* q_w1 = (const float*)d_in[3];  const float* q_b1 = (const float*)d_in[4];
    const float* q_w2 = (const float*)d_in[5];  const float* q_b2 = (const float*)d_in[6];
    const float* q_w3 = (const float*)d_in[7];  const float* q_b3 = (const float*)d_in[8];
    const float* k_w1 = (const float*)d_in[9];  const float* k_b1 = (const float*)d_in[10];
    const float* k_w2 = (const float*)d_in[11]; const float* k_b2 = (const float*)d_in[12];
    const float* k_w3 = (const float*)d_in[13]; const float* k_b3 = (const float*)d_in[14];
    const float* v_w1 = (const float*)d_in[15]; const float* v_b1 = (const float*)d_in[16];
    const float* v_w2 = (const float*)d_in[17]; const float* v_b2 = (const float*)d_in[18];
    const float* v_w3 = (const float*)d_in[19]; const float* v_b3 = (const float*)d_in[20];
    const float* o_w1 = (const float*)d_in[21]; const float* o_b1 = (const float*)d_in[22];
    const float* o_w2 = (const float*)d_in[23]; const float* o_b2 = (const float*)d_in[24];

    // workspace (ushort units)
    unsigned short* ws = (unsigned short*)d_ws;
    unsigned short* field_bf = ws;                 // 8,388,608
    unsigned short* efeat_bf = ws + 8388608;       // 32,000
    unsigned short* wt       = ws + 8420608;       // 1,736,704
    unsigned short* qbuf     = ws + 10157312;      // 128,000
    unsigned short* kbuf     = ws + 10285312;      // 8,388,608
    unsigned short* vtb      = ws + 18673920;      // 8,388,608

    // conversions + packed weight transform
    f32_to_bf16<<<dim3(2048), dim3(256), 0, stream>>>(field, field_bf, 1048576);
    f32_to_bf16<<<dim3(16),   dim3(256), 0, stream>>>(efeat, efeat_bf, 4000);
    wt_pack<<<dim3(8, 8, 11), dim3(256), 0, stream>>>(
        q_w1, q_w2, q_w3, k_w1, k_w2, k_w3, v_w1, v_w2, v_w3, o_w1, o_w2, wt);

    // q + k + v MLPs (2064 blocks x 512 threads, 32 rows/block, 3 blocks/CU)
    fused_qkv<<<dim3(2064), dim3(512), 0, stream>>>(
        field_bf, efeat_bf, wt, q_b1, q_b2, q_b3, k_b1, k_b2, k_b3,
        v_b1, v_b2, v_b3, qbuf, kbuf, vtb);

    // fused attention + o-MLP (stores f32 output directly)
    attn_fused<<<dim3(512), dim3(512), 0, stream>>>(
        qbuf, kbuf, vtb, mask, wt, o_b1, o_b2, (float*)d_out);
}